// Round 5
// baseline (1373.817 us; speedup 1.0000x reference)
//
#include <hip/hip_runtime.h>

#define NENT 40000
#define NRELH 200   /* (N_REL-1)/2 */
#define NLAYER 6
#define NEDGE 300000

// y layout: [node][d][b]  (idx = (n*64 + d)*4 + b): y[h][*][0..3] is a
// contiguous 1KB block one wave gathers with a single float4/lane instruction.

// ---------------- graph preprocessing (CSR build) ----------------

__global__ void k_count(const int* __restrict__ tri, int* __restrict__ cnt,
                        int* __restrict__ degm) {
  int e = blockIdx.x * blockDim.x + threadIdx.x;
  if (e >= NEDGE) return;
  int r = tri[3*e+1], t = tri[3*e+2];
  atomicAdd(&cnt[t], 1);
  if (r >= 1 && r < NRELH) atomicAdd(&degm[t], 1);
}

__global__ void k_scan(const int* __restrict__ cnt, int* __restrict__ off) {
  __shared__ int part[1024];
  int tid = threadIdx.x;
  int base = tid * 40;             // 1024*40 = 40960 >= NENT
  int s = 0;
  for (int i = 0; i < 40; ++i) { int idx = base + i; if (idx < NENT) s += cnt[idx]; }
  part[tid] = s;
  __syncthreads();
  for (int dd = 1; dd < 1024; dd <<= 1) {
    int v = (tid >= dd) ? part[tid - dd] : 0;
    __syncthreads();
    part[tid] += v;
    __syncthreads();
  }
  int run = part[tid] - s;
  for (int i = 0; i < 40; ++i) {
    int idx = base + i;
    if (idx < NENT) { off[idx] = run; run += cnt[idx]; }
  }
  if (tid == 1023) off[NENT] = part[1023];
}

__global__ void k_fill(const int* __restrict__ tri, const int* __restrict__ off,
                       int* __restrict__ cur, unsigned* __restrict__ ehr) {
  int e = blockIdx.x * blockDim.x + threadIdx.x;
  if (e >= NEDGE) return;
  int h = tri[3*e], r = tri[3*e+1], t = tri[3*e+2];
  int pos = off[t] + atomicAdd(&cur[t], 1);
  ehr[pos] = (unsigned)h | ((unsigned)r << 16);   // h < 65536, r < 512
}

// ---------------- layer 0 init: y0 = x0 @ We0^T + be0 ----------------

__global__ __launch_bounds__(1024, 8)
void k_init(const float* __restrict__ We, const float* __restrict__ be,
            float* __restrict__ y, const float* __restrict__ ent,
            const float* __restrict__ qe, const int* __restrict__ head,
            const int* __restrict__ rel, const int* __restrict__ degm) {
  __shared__ float sWT[4096];   // WT[k][e] = We[e][k]
  __shared__ float sc[4096];    // 16 waves x 256 floats scratch
  int tid = threadIdx.x, lane = tid & 63, wv = tid >> 6;
  {
    int e = tid >> 4, k4 = (tid & 15) * 4;    // 1024 threads cover 64x16
    float4 w = *reinterpret_cast<const float4*>(We + e*64 + k4);
    sWT[(k4+0)*64+e] = w.x; sWT[(k4+1)*64+e] = w.y;
    sWT[(k4+2)*64+e] = w.z; sWT[(k4+3)*64+e] = w.w;
  }
  __syncthreads();
  float bv = be[lane];
  int h0=head[0], h1=head[1], h2=head[2], h3=head[3];
  int r0=rel[0],  r1=rel[1],  r2=rel[2],  r3=rel[3];
  float* wsc = sc + wv*256;
  int stride = gridDim.x*16;
  for (int n = blockIdx.x*16 + wv; n < NENT; n += stride) {
    float basev = (degm[n] >= 3) ? ent[(size_t)n*64 + lane] : -0.375f; // 1/8-0.5
    float4 xv;
    xv.x = (h0==n) ? qe[r0*64+lane] : basev;
    xv.y = (h1==n) ? qe[r1*64+lane] : basev;
    xv.z = (h2==n) ? qe[r2*64+lane] : basev;
    xv.w = (h3==n) ? qe[r3*64+lane] : basev;
    *reinterpret_cast<float4*>(wsc + lane*4) = xv;      // lane holds x[d=lane][0..3]
    float4 acc = make_float4(bv, bv, bv, bv);
    #pragma unroll 8
    for (int k = 0; k < 64; ++k) {
      float4 u = *reinterpret_cast<const float4*>(wsc + k*4);  // uniform broadcast
      float  w = sWT[k*64 + lane];                             // lane = output e
      acc.x = fmaf(u.x, w, acc.x); acc.y = fmaf(u.y, w, acc.y);
      acc.z = fmaf(u.z, w, acc.z); acc.w = fmaf(u.w, w, acc.w);
    }
    *reinterpret_cast<float4*>(y + ((size_t)n*64 + lane)*4) = acc;
  }
}

// ---------------- fused layer kernel ----------------
// upd = segsum(relw[r] o y[h]);  z = upd @ Wl^T + bl + y[n];  xn = relu(LN(z));
// !LAST: y_next[n] = xn @ We_next^T + be_next      LAST: out[b][n] = xn . wcls + bc
//
// SCHEME 0: weights column-major (WT[k][e]); scratch [d][b]; per matmul:
//           64 uniform ds_read_b128 + 64 per-lane b32.
// SCHEME 1: weights row-major XOR-swizzled (slot = k4 ^ (e&15)); scratch [b][d];
//           per matmul: 64 uniform ds_read_b128 + 16 per-lane b128 (conflict-free).

template<int SCHEME, bool LAST>
__global__ __launch_bounds__(1024, 8)
void k_fused(const float* __restrict__ y, const unsigned* __restrict__ ehr,
             const int* __restrict__ off, const float* __restrict__ relw,
             const float* __restrict__ Wl, const float* __restrict__ bl,
             const float* __restrict__ lng, const float* __restrict__ lnb,
             const float* __restrict__ Wen, const float* __restrict__ ben,
             const float* __restrict__ wcls, const float* __restrict__ bcls,
             float* __restrict__ ynext, float* __restrict__ out) {
  __shared__ float sWl[4096];
  __shared__ float sWe[4096];   // unused when LAST
  __shared__ float sc[4096];    // 16 waves x 256 floats scratch
  int tid = threadIdx.x, lane = tid & 63, wv = tid >> 6;
  {
    int e = tid >> 4, j = tid & 15;           // 1024 threads cover 64x16
    float4 w = *reinterpret_cast<const float4*>(Wl + e*64 + 4*j);
    if (SCHEME == 0) {
      int k4 = 4*j;
      sWl[(k4+0)*64+e] = w.x; sWl[(k4+1)*64+e] = w.y;
      sWl[(k4+2)*64+e] = w.z; sWl[(k4+3)*64+e] = w.w;
    } else {
      *reinterpret_cast<float4*>(&sWl[e*64 + ((j ^ (e & 15)) * 4)]) = w;
    }
    if (!LAST) {
      float4 v = *reinterpret_cast<const float4*>(Wen + e*64 + 4*j);
      if (SCHEME == 0) {
        int k4 = 4*j;
        sWe[(k4+0)*64+e] = v.x; sWe[(k4+1)*64+e] = v.y;
        sWe[(k4+2)*64+e] = v.z; sWe[(k4+3)*64+e] = v.w;
      } else {
        *reinterpret_cast<float4*>(&sWe[e*64 + ((j ^ (e & 15)) * 4)]) = v;
      }
    }
  }
  __syncthreads();
  float blv = bl[lane], g = lng[lane], bb = lnb[lane];
  float bev = LAST ? 0.f : ben[lane];
  float wc  = LAST ? wcls[lane] : 0.f;
  float bc  = LAST ? bcls[0] : 0.f;
  float* wsc = sc + wv*256;
  int stride = gridDim.x*16;
  for (int n = blockIdx.x*16 + wv; n < NENT; n += stride) {
    int c0 = __builtin_amdgcn_readfirstlane(off[n]);
    int c1 = __builtin_amdgcn_readfirstlane(off[n+1]);
    // residual load issued early, overlaps the gather
    float4 res = *reinterpret_cast<const float4*>(y + ((size_t)n*64 + lane)*4);
    float4 a0 = make_float4(0,0,0,0), a1 = make_float4(0,0,0,0);
    for (int j = c0; j < c1; j += 4) {
      int j1 = (j+1 < c1) ? j+1 : j;
      int j2 = (j+2 < c1) ? j+2 : j;
      int j3 = (j+3 < c1) ? j+3 : j;
      unsigned e0 = ehr[j], e1 = ehr[j1], e2 = ehr[j2], e3 = ehr[j3];
      float m1 = (j+1 < c1) ? 1.f : 0.f;
      float m2 = (j+2 < c1) ? 1.f : 0.f;
      float m3 = (j+3 < c1) ? 1.f : 0.f;
      int ha = (int)(e0 & 0xffffu), ra = (int)(e0 >> 16);
      int hb = (int)(e1 & 0xffffu), rb = (int)(e1 >> 16);
      int hc = (int)(e2 & 0xffffu), rc = (int)(e2 >> 16);
      int hd = (int)(e3 & 0xffffu), rd = (int)(e3 >> 16);
      float w0 = relw[ra*64 + lane];
      float w1 = relw[rb*64 + lane] * m1;
      float w2 = relw[rc*64 + lane] * m2;
      float w3 = relw[rd*64 + lane] * m3;
      float4 v0 = *reinterpret_cast<const float4*>(y + ((size_t)ha*64 + lane)*4);
      float4 v1 = *reinterpret_cast<const float4*>(y + ((size_t)hb*64 + lane)*4);
      float4 v2 = *reinterpret_cast<const float4*>(y + ((size_t)hc*64 + lane)*4);
      float4 v3 = *reinterpret_cast<const float4*>(y + ((size_t)hd*64 + lane)*4);
      a0.x = fmaf(w0, v0.x, a0.x); a0.y = fmaf(w0, v0.y, a0.y);
      a0.z = fmaf(w0, v0.z, a0.z); a0.w = fmaf(w0, v0.w, a0.w);
      a1.x = fmaf(w1, v1.x, a1.x); a1.y = fmaf(w1, v1.y, a1.y);
      a1.z = fmaf(w1, v1.z, a1.z); a1.w = fmaf(w1, v1.w, a1.w);
      a0.x = fmaf(w2, v2.x, a0.x); a0.y = fmaf(w2, v2.y, a0.y);
      a0.z = fmaf(w2, v2.z, a0.z); a0.w = fmaf(w2, v2.w, a0.w);
      a1.x = fmaf(w3, v3.x, a1.x); a1.y = fmaf(w3, v3.y, a1.y);
      a1.z = fmaf(w3, v3.z, a1.z); a1.w = fmaf(w3, v3.w, a1.w);
    }
    float4 acc = make_float4(a0.x+a1.x, a0.y+a1.y, a0.z+a1.z, a0.w+a1.w);
    float4 z = make_float4(blv+res.x, blv+res.y, blv+res.z, blv+res.w);
    if (SCHEME == 0) {
      *reinterpret_cast<float4*>(wsc + lane*4) = acc;   // scratch [d][b]
      #pragma unroll 8
      for (int k = 0; k < 64; ++k) {
        float4 u = *reinterpret_cast<const float4*>(wsc + k*4);  // uniform
        float  w = sWl[k*64 + lane];                             // lane = e
        z.x = fmaf(u.x, w, z.x); z.y = fmaf(u.y, w, z.y);
        z.z = fmaf(u.z, w, z.z); z.w = fmaf(u.w, w, z.w);
      }
    } else {
      wsc[  0+lane] = acc.x; wsc[ 64+lane] = acc.y;     // scratch [b][d]
      wsc[128+lane] = acc.z; wsc[192+lane] = acc.w;
      #pragma unroll
      for (int k4 = 0; k4 < 16; ++k4) {
        float4 w4 = *reinterpret_cast<const float4*>(&sWl[lane*64 + ((k4 ^ (lane & 15)) * 4)]);
        float4 u0 = *reinterpret_cast<const float4*>(wsc +   0 + k4*4);  // uniform
        float4 u1 = *reinterpret_cast<const float4*>(wsc +  64 + k4*4);
        float4 u2 = *reinterpret_cast<const float4*>(wsc + 128 + k4*4);
        float4 u3 = *reinterpret_cast<const float4*>(wsc + 192 + k4*4);
        z.x = fmaf(u0.x, w4.x, z.x); z.x = fmaf(u0.y, w4.y, z.x);
        z.x = fmaf(u0.z, w4.z, z.x); z.x = fmaf(u0.w, w4.w, z.x);
        z.y = fmaf(u1.x, w4.x, z.y); z.y = fmaf(u1.y, w4.y, z.y);
        z.y = fmaf(u1.z, w4.z, z.y); z.y = fmaf(u1.w, w4.w, z.y);
        z.z = fmaf(u2.x, w4.x, z.z); z.z = fmaf(u2.y, w4.y, z.z);
        z.z = fmaf(u2.z, w4.z, z.z); z.z = fmaf(u2.w, w4.w, z.z);
        z.w = fmaf(u3.x, w4.x, z.w); z.w = fmaf(u3.y, w4.y, z.w);
        z.w = fmaf(u3.z, w4.z, z.w); z.w = fmaf(u3.w, w4.w, z.w);
      }
    }
    // LayerNorm over the 64 lanes (feature dim), then ReLU
    float4 s = z;
    #pragma unroll
    for (int m = 32; m >= 1; m >>= 1) {
      s.x += __shfl_xor(s.x, m, 64); s.y += __shfl_xor(s.y, m, 64);
      s.z += __shfl_xor(s.z, m, 64); s.w += __shfl_xor(s.w, m, 64);
    }
    float4 dv = make_float4(z.x - s.x*0.015625f, z.y - s.y*0.015625f,
                            z.z - s.z*0.015625f, z.w - s.w*0.015625f);
    float4 q = make_float4(dv.x*dv.x, dv.y*dv.y, dv.z*dv.z, dv.w*dv.w);
    #pragma unroll
    for (int m = 32; m >= 1; m >>= 1) {
      q.x += __shfl_xor(q.x, m, 64); q.y += __shfl_xor(q.y, m, 64);
      q.z += __shfl_xor(q.z, m, 64); q.w += __shfl_xor(q.w, m, 64);
    }
    float4 xn;
    xn.x = fmaxf(dv.x * rsqrtf(q.x*0.015625f + 1e-5f) * g + bb, 0.f);
    xn.y = fmaxf(dv.y * rsqrtf(q.y*0.015625f + 1e-5f) * g + bb, 0.f);
    xn.z = fmaxf(dv.z * rsqrtf(q.z*0.015625f + 1e-5f) * g + bb, 0.f);
    xn.w = fmaxf(dv.w * rsqrtf(q.w*0.015625f + 1e-5f) * g + bb, 0.f);
    if (LAST) {
      float4 p = make_float4(xn.x*wc, xn.y*wc, xn.z*wc, xn.w*wc);
      #pragma unroll
      for (int m = 32; m >= 1; m >>= 1) {
        p.x += __shfl_xor(p.x, m, 64); p.y += __shfl_xor(p.y, m, 64);
        p.z += __shfl_xor(p.z, m, 64); p.w += __shfl_xor(p.w, m, 64);
      }
      float pv = (lane == 0) ? p.x : (lane == 1) ? p.y : (lane == 2) ? p.z : p.w;
      if (lane < 4) out[(size_t)lane*NENT + n] = pv + bc;
    } else {
      // fused next-layer entity matmul: y_next = xn @ We_next^T + be_next
      float4 yn = make_float4(bev, bev, bev, bev);
      if (SCHEME == 0) {
        *reinterpret_cast<float4*>(wsc + lane*4) = xn;
        #pragma unroll 8
        for (int k = 0; k < 64; ++k) {
          float4 u = *reinterpret_cast<const float4*>(wsc + k*4);  // uniform
          float  w = sWe[k*64 + lane];
          yn.x = fmaf(u.x, w, yn.x); yn.y = fmaf(u.y, w, yn.y);
          yn.z = fmaf(u.z, w, yn.z); yn.w = fmaf(u.w, w, yn.w);
        }
      } else {
        wsc[  0+lane] = xn.x; wsc[ 64+lane] = xn.y;
        wsc[128+lane] = xn.z; wsc[192+lane] = xn.w;
        #pragma unroll
        for (int k4 = 0; k4 < 16; ++k4) {
          float4 w4 = *reinterpret_cast<const float4*>(&sWe[lane*64 + ((k4 ^ (lane & 15)) * 4)]);
          float4 u0 = *reinterpret_cast<const float4*>(wsc +   0 + k4*4);
          float4 u1 = *reinterpret_cast<const float4*>(wsc +  64 + k4*4);
          float4 u2 = *reinterpret_cast<const float4*>(wsc + 128 + k4*4);
          float4 u3 = *reinterpret_cast<const float4*>(wsc + 192 + k4*4);
          yn.x = fmaf(u0.x, w4.x, yn.x); yn.x = fmaf(u0.y, w4.y, yn.x);
          yn.x = fmaf(u0.z, w4.z, yn.x); yn.x = fmaf(u0.w, w4.w, yn.x);
          yn.y = fmaf(u1.x, w4.x, yn.y); yn.y = fmaf(u1.y, w4.y, yn.y);
          yn.y = fmaf(u1.z, w4.z, yn.y); yn.y = fmaf(u1.w, w4.w, yn.y);
          yn.z = fmaf(u2.x, w4.x, yn.z); yn.z = fmaf(u2.y, w4.y, yn.z);
          yn.z = fmaf(u2.z, w4.z, yn.z); yn.z = fmaf(u2.w, w4.w, yn.z);
          yn.w = fmaf(u3.x, w4.x, yn.w); yn.w = fmaf(u3.y, w4.y, yn.w);
          yn.w = fmaf(u3.z, w4.z, yn.w); yn.w = fmaf(u3.w, w4.w, yn.w);
        }
      }
      *reinterpret_cast<float4*>(ynext + ((size_t)n*64 + lane)*4) = yn;
    }
  }
}

// ---------------- launch ----------------

extern "C" void kernel_launch(void* const* d_in, const int* in_sizes, int n_in,
                              void* d_out, int out_size, void* d_ws, size_t ws_size,
                              hipStream_t stream) {
  const int*   head = (const int*)  d_in[0];
  const int*   rel  = (const int*)  d_in[1];
  const int*   tri  = (const int*)  d_in[2];
  const float* ent  = (const float*)d_in[3];
  const float* qe   = (const float*)d_in[4];
  const float* rw   = (const float*)d_in[5];
  const float* We   = (const float*)d_in[6];
  const float* be   = (const float*)d_in[7];
  const float* Wl   = (const float*)d_in[8];
  const float* bl   = (const float*)d_in[9];
  const float* lg   = (const float*)d_in[10];
  const float* lb   = (const float*)d_in[11];
  const float* wc   = (const float*)d_in[12];
  const float* bc   = (const float*)d_in[13];

  char* ws = (char*)d_ws;
  size_t o = 0;
  auto alloc = [&](size_t bytes) { void* p = ws + o; o += (bytes + 255) & ~255ull; return p; };
  float*    ya   = (float*)   alloc((size_t)NENT*256*sizeof(float)); // 41 MB, [n][d][b]
  float*    yb   = (float*)   alloc((size_t)NENT*256*sizeof(float)); // 41 MB, [n][d][b]
  int*      cnt  = (int*)     alloc(NENT*sizeof(int));   // cnt, degm, cur contiguous
  int*      degm = (int*)     alloc(NENT*sizeof(int));   // (NENT*4 % 256 == 0)
  int*      cur  = (int*)     alloc(NENT*sizeof(int));
  int*      off  = (int*)     alloc((NENT+1)*sizeof(int));
  unsigned* ehr  = (unsigned*)alloc(NEDGE*sizeof(unsigned));
  (void)ws_size; (void)in_sizes; (void)n_in; (void)out_size;

  hipMemsetAsync(cnt, 0, (size_t)3*NENT*sizeof(int), stream);  // cnt, degm, cur

  k_count<<<(NEDGE+255)/256, 256, 0, stream>>>(tri, cnt, degm);
  k_scan <<<1, 1024, 0, stream>>>(cnt, off);
  k_fill <<<(NEDGE+255)/256, 256, 0, stream>>>(tri, off, cur, ehr);

  const int GRID = 512;   // 2 blocks/CU x 16 waves = 32 waves/CU, grid-stride
  k_init<<<GRID, 1024, 0, stream>>>(We, be, ya, ent, qe, head, rel, degm);

  for (int i = 0; i < NLAYER; ++i) {
    const float* src = (i % 2 == 0) ? ya : yb;
    float*       dst = (i % 2 == 0) ? yb : ya;
    const float* Wli = Wl + (size_t)i*4096;
    const float* bli = bl + (size_t)i*64;
    const float* rwi = rw + (size_t)i*401*64;
    const float* lgi = lg + (size_t)i*64;
    const float* lbi = lb + (size_t)i*64;
    const float* Wen = We + (size_t)(i+1)*4096;  // next layer's entity matmul
    const float* ben = be + (size_t)(i+1)*64;
    if (i == NLAYER-1)
      k_fused<0, true ><<<GRID, 1024, 0, stream>>>(src, ehr, off, rwi, Wli, bli, lgi, lbi,
                                                   We, be, wc, bc, dst, (float*)d_out);
    else if (i % 2 == 0)   // layers 0,2,4 -> SCHEME 0 (A)
      k_fused<0, false><<<GRID, 1024, 0, stream>>>(src, ehr, off, rwi, Wli, bli, lgi, lbi,
                                                   Wen, ben, wc, bc, dst, (float*)d_out);
    else                   // layers 1,3 -> SCHEME 1 (B)
      k_fused<1, false><<<GRID, 1024, 0, stream>>>(src, ehr, off, rwi, Wli, bli, lgi, lbi,
                                                   Wen, ben, wc, bc, dst, (float*)d_out);
  }
}

// Round 6
// 1013.268 us; speedup vs baseline: 1.3558x; 1.3558x over previous
//
#include <hip/hip_runtime.h>

#define NENT 40000
#define NRELH 200   /* (N_REL-1)/2 */
#define NLAYER 6
#define NEDGE 300000

// y layout: [node][d][b]  (idx = (n*64 + d)*4 + b): y[h][*][0..3] is a
// contiguous 1KB block one wave gathers with a single float4/lane instruction.

// ---------------- graph preprocessing (CSR build) ----------------

__global__ void k_count(const int* __restrict__ tri, int* __restrict__ cnt,
                        int* __restrict__ degm) {
  int e = blockIdx.x * blockDim.x + threadIdx.x;
  if (e >= NEDGE) return;
  int r = tri[3*e+1], t = tri[3*e+2];
  atomicAdd(&cnt[t], 1);
  if (r >= 1 && r < NRELH) atomicAdd(&degm[t], 1);
}

__global__ void k_scan(const int* __restrict__ cnt, int* __restrict__ off) {
  __shared__ int part[1024];
  int tid = threadIdx.x;
  int base = tid * 40;             // 1024*40 = 40960 >= NENT
  int s = 0;
  for (int i = 0; i < 40; ++i) { int idx = base + i; if (idx < NENT) s += cnt[idx]; }
  part[tid] = s;
  __syncthreads();
  for (int dd = 1; dd < 1024; dd <<= 1) {
    int v = (tid >= dd) ? part[tid - dd] : 0;
    __syncthreads();
    part[tid] += v;
    __syncthreads();
  }
  int run = part[tid] - s;
  for (int i = 0; i < 40; ++i) {
    int idx = base + i;
    if (idx < NENT) { off[idx] = run; run += cnt[idx]; }
  }
  if (tid == 1023) off[NENT] = part[1023];
}

__global__ void k_fill(const int* __restrict__ tri, const int* __restrict__ off,
                       int* __restrict__ cur, unsigned* __restrict__ ehr) {
  int e = blockIdx.x * blockDim.x + threadIdx.x;
  if (e >= NEDGE) return;
  int h = tri[3*e], r = tri[3*e+1], t = tri[3*e+2];
  int pos = off[t] + atomicAdd(&cur[t], 1);
  ehr[pos] = (unsigned)h | ((unsigned)r << 16);   // h < 65536, r < 512
}

// ---------------- layer 0 init: y0 = x0 @ We0^T + be0 ----------------

__global__ __launch_bounds__(512, 4)
void k_init(const float* __restrict__ We, const float* __restrict__ be,
            float* __restrict__ y, const float* __restrict__ ent,
            const float* __restrict__ qe, const int* __restrict__ head,
            const int* __restrict__ rel, const int* __restrict__ degm) {
  __shared__ float sWT[4096];   // WT[k][e] = We[e][k]
  __shared__ float sc[2048];    // 8 waves x 256 floats scratch
  int tid = threadIdx.x, lane = tid & 63, wv = tid >> 6;
  for (int idx = tid; idx < 1024; idx += 512) {
    int e = idx >> 4, k4 = (idx & 15) * 4;
    float4 w = *reinterpret_cast<const float4*>(We + e*64 + k4);
    sWT[(k4+0)*64+e] = w.x; sWT[(k4+1)*64+e] = w.y;
    sWT[(k4+2)*64+e] = w.z; sWT[(k4+3)*64+e] = w.w;
  }
  __syncthreads();
  float bv = be[lane];
  int h0=head[0], h1=head[1], h2=head[2], h3=head[3];
  int r0=rel[0],  r1=rel[1],  r2=rel[2],  r3=rel[3];
  float* wsc = sc + wv*256;
  int stride = gridDim.x*8;
  for (int n = blockIdx.x*8 + wv; n < NENT; n += stride) {
    float basev = (degm[n] >= 3) ? ent[(size_t)n*64 + lane] : -0.375f; // 1/8-0.5
    float4 xv;
    xv.x = (h0==n) ? qe[r0*64+lane] : basev;
    xv.y = (h1==n) ? qe[r1*64+lane] : basev;
    xv.z = (h2==n) ? qe[r2*64+lane] : basev;
    xv.w = (h3==n) ? qe[r3*64+lane] : basev;
    *reinterpret_cast<float4*>(wsc + lane*4) = xv;      // lane holds x[d=lane][0..3]
    float4 acc = make_float4(bv, bv, bv, bv);
    #pragma unroll 8
    for (int k = 0; k < 64; ++k) {
      float4 u = *reinterpret_cast<const float4*>(wsc + k*4);  // uniform broadcast
      float  w = sWT[k*64 + lane];                             // lane = output e
      acc.x = fmaf(u.x, w, acc.x); acc.y = fmaf(u.y, w, acc.y);
      acc.z = fmaf(u.z, w, acc.z); acc.w = fmaf(u.w, w, acc.w);
    }
    *reinterpret_cast<float4*>(y + ((size_t)n*64 + lane)*4) = acc;
  }
}

// ---------------- fused layer kernel ----------------
// upd = segsum(relw[r] o y[h]);  z = upd @ Wl^T + bl + y[n];  xn = relu(LN(z));
// !LAST: y_next[n] = xn @ We_next^T + be_next      LAST: out[b][n] = xn . wcls + bc
//
// SCHEME 0: weights column-major (WT[k][e]); scratch [d][b]; per matmul:
//           64 uniform ds_read_b128 + 64 per-lane b32.
// SCHEME 1: weights row-major XOR-swizzled (slot = k4 ^ (e&15)); scratch [b][d];
//           per matmul: 64 uniform ds_read_b128 + 16 per-lane b128 (conflict-free).

template<int SCHEME, bool LAST>
__global__ __launch_bounds__(512, 4)
void k_fused(const float* __restrict__ y, const unsigned* __restrict__ ehr,
             const int* __restrict__ off, const float* __restrict__ relw,
             const float* __restrict__ Wl, const float* __restrict__ bl,
             const float* __restrict__ lng, const float* __restrict__ lnb,
             const float* __restrict__ Wen, const float* __restrict__ ben,
             const float* __restrict__ wcls, const float* __restrict__ bcls,
             float* __restrict__ ynext, float* __restrict__ out) {
  __shared__ float sWl[4096];
  __shared__ float sWe[4096];   // unused when LAST
  __shared__ float sc[2048];    // 8 waves x 256 floats scratch
  int tid = threadIdx.x, lane = tid & 63, wv = tid >> 6;
  for (int idx = tid; idx < 1024; idx += 512) {
    int e = idx >> 4, j = idx & 15;
    float4 w = *reinterpret_cast<const float4*>(Wl + e*64 + 4*j);
    if (SCHEME == 0) {
      int k4 = 4*j;
      sWl[(k4+0)*64+e] = w.x; sWl[(k4+1)*64+e] = w.y;
      sWl[(k4+2)*64+e] = w.z; sWl[(k4+3)*64+e] = w.w;
    } else {
      *reinterpret_cast<float4*>(&sWl[e*64 + ((j ^ (e & 15)) * 4)]) = w;
    }
    if (!LAST) {
      float4 v = *reinterpret_cast<const float4*>(Wen + e*64 + 4*j);
      if (SCHEME == 0) {
        int k4 = 4*j;
        sWe[(k4+0)*64+e] = v.x; sWe[(k4+1)*64+e] = v.y;
        sWe[(k4+2)*64+e] = v.z; sWe[(k4+3)*64+e] = v.w;
      } else {
        *reinterpret_cast<float4*>(&sWe[e*64 + ((j ^ (e & 15)) * 4)]) = v;
      }
    }
  }
  __syncthreads();
  float blv = bl[lane], g = lng[lane], bb = lnb[lane];
  float bev = LAST ? 0.f : ben[lane];
  float wc  = LAST ? wcls[lane] : 0.f;
  float bc  = LAST ? bcls[0] : 0.f;
  float* wsc = sc + wv*256;
  int stride = gridDim.x*8;
  for (int n = blockIdx.x*8 + wv; n < NENT; n += stride) {
    int c0 = __builtin_amdgcn_readfirstlane(off[n]);
    int c1 = __builtin_amdgcn_readfirstlane(off[n+1]);
    // residual load issued early, overlaps the gather
    float4 res = *reinterpret_cast<const float4*>(y + ((size_t)n*64 + lane)*4);
    float4 a0 = make_float4(0,0,0,0), a1 = make_float4(0,0,0,0);
    for (int j = c0; j < c1; j += 4) {
      int j1 = (j+1 < c1) ? j+1 : j;
      int j2 = (j+2 < c1) ? j+2 : j;
      int j3 = (j+3 < c1) ? j+3 : j;
      unsigned e0 = ehr[j], e1 = ehr[j1], e2 = ehr[j2], e3 = ehr[j3];
      float m1 = (j+1 < c1) ? 1.f : 0.f;
      float m2 = (j+2 < c1) ? 1.f : 0.f;
      float m3 = (j+3 < c1) ? 1.f : 0.f;
      int ha = (int)(e0 & 0xffffu), ra = (int)(e0 >> 16);
      int hb = (int)(e1 & 0xffffu), rb = (int)(e1 >> 16);
      int hc = (int)(e2 & 0xffffu), rc = (int)(e2 >> 16);
      int hd = (int)(e3 & 0xffffu), rd = (int)(e3 >> 16);
      float w0 = relw[ra*64 + lane];
      float w1 = relw[rb*64 + lane] * m1;
      float w2 = relw[rc*64 + lane] * m2;
      float w3 = relw[rd*64 + lane] * m3;
      float4 v0 = *reinterpret_cast<const float4*>(y + ((size_t)ha*64 + lane)*4);
      float4 v1 = *reinterpret_cast<const float4*>(y + ((size_t)hb*64 + lane)*4);
      float4 v2 = *reinterpret_cast<const float4*>(y + ((size_t)hc*64 + lane)*4);
      float4 v3 = *reinterpret_cast<const float4*>(y + ((size_t)hd*64 + lane)*4);
      a0.x = fmaf(w0, v0.x, a0.x); a0.y = fmaf(w0, v0.y, a0.y);
      a0.z = fmaf(w0, v0.z, a0.z); a0.w = fmaf(w0, v0.w, a0.w);
      a1.x = fmaf(w1, v1.x, a1.x); a1.y = fmaf(w1, v1.y, a1.y);
      a1.z = fmaf(w1, v1.z, a1.z); a1.w = fmaf(w1, v1.w, a1.w);
      a0.x = fmaf(w2, v2.x, a0.x); a0.y = fmaf(w2, v2.y, a0.y);
      a0.z = fmaf(w2, v2.z, a0.z); a0.w = fmaf(w2, v2.w, a0.w);
      a1.x = fmaf(w3, v3.x, a1.x); a1.y = fmaf(w3, v3.y, a1.y);
      a1.z = fmaf(w3, v3.z, a1.z); a1.w = fmaf(w3, v3.w, a1.w);
    }
    float4 acc = make_float4(a0.x+a1.x, a0.y+a1.y, a0.z+a1.z, a0.w+a1.w);
    float4 z = make_float4(blv+res.x, blv+res.y, blv+res.z, blv+res.w);
    if (SCHEME == 0) {
      *reinterpret_cast<float4*>(wsc + lane*4) = acc;   // scratch [d][b]
      #pragma unroll 8
      for (int k = 0; k < 64; ++k) {
        float4 u = *reinterpret_cast<const float4*>(wsc + k*4);  // uniform
        float  w = sWl[k*64 + lane];                             // lane = e
        z.x = fmaf(u.x, w, z.x); z.y = fmaf(u.y, w, z.y);
        z.z = fmaf(u.z, w, z.z); z.w = fmaf(u.w, w, z.w);
      }
    } else {
      wsc[  0+lane] = acc.x; wsc[ 64+lane] = acc.y;     // scratch [b][d]
      wsc[128+lane] = acc.z; wsc[192+lane] = acc.w;
      #pragma unroll
      for (int k4 = 0; k4 < 16; ++k4) {
        float4 w4 = *reinterpret_cast<const float4*>(&sWl[lane*64 + ((k4 ^ (lane & 15)) * 4)]);
        float4 u0 = *reinterpret_cast<const float4*>(wsc +   0 + k4*4);  // uniform
        float4 u1 = *reinterpret_cast<const float4*>(wsc +  64 + k4*4);
        float4 u2 = *reinterpret_cast<const float4*>(wsc + 128 + k4*4);
        float4 u3 = *reinterpret_cast<const float4*>(wsc + 192 + k4*4);
        z.x = fmaf(u0.x, w4.x, z.x); z.x = fmaf(u0.y, w4.y, z.x);
        z.x = fmaf(u0.z, w4.z, z.x); z.x = fmaf(u0.w, w4.w, z.x);
        z.y = fmaf(u1.x, w4.x, z.y); z.y = fmaf(u1.y, w4.y, z.y);
        z.y = fmaf(u1.z, w4.z, z.y); z.y = fmaf(u1.w, w4.w, z.y);
        z.z = fmaf(u2.x, w4.x, z.z); z.z = fmaf(u2.y, w4.y, z.z);
        z.z = fmaf(u2.z, w4.z, z.z); z.z = fmaf(u2.w, w4.w, z.z);
        z.w = fmaf(u3.x, w4.x, z.w); z.w = fmaf(u3.y, w4.y, z.w);
        z.w = fmaf(u3.z, w4.z, z.w); z.w = fmaf(u3.w, w4.w, z.w);
      }
    }
    // LayerNorm over the 64 lanes (feature dim), then ReLU
    float4 s = z;
    #pragma unroll
    for (int m = 32; m >= 1; m >>= 1) {
      s.x += __shfl_xor(s.x, m, 64); s.y += __shfl_xor(s.y, m, 64);
      s.z += __shfl_xor(s.z, m, 64); s.w += __shfl_xor(s.w, m, 64);
    }
    float4 dv = make_float4(z.x - s.x*0.015625f, z.y - s.y*0.015625f,
                            z.z - s.z*0.015625f, z.w - s.w*0.015625f);
    float4 q = make_float4(dv.x*dv.x, dv.y*dv.y, dv.z*dv.z, dv.w*dv.w);
    #pragma unroll
    for (int m = 32; m >= 1; m >>= 1) {
      q.x += __shfl_xor(q.x, m, 64); q.y += __shfl_xor(q.y, m, 64);
      q.z += __shfl_xor(q.z, m, 64); q.w += __shfl_xor(q.w, m, 64);
    }
    float4 xn;
    xn.x = fmaxf(dv.x * rsqrtf(q.x*0.015625f + 1e-5f) * g + bb, 0.f);
    xn.y = fmaxf(dv.y * rsqrtf(q.y*0.015625f + 1e-5f) * g + bb, 0.f);
    xn.z = fmaxf(dv.z * rsqrtf(q.z*0.015625f + 1e-5f) * g + bb, 0.f);
    xn.w = fmaxf(dv.w * rsqrtf(q.w*0.015625f + 1e-5f) * g + bb, 0.f);
    if (LAST) {
      float4 p = make_float4(xn.x*wc, xn.y*wc, xn.z*wc, xn.w*wc);
      #pragma unroll
      for (int m = 32; m >= 1; m >>= 1) {
        p.x += __shfl_xor(p.x, m, 64); p.y += __shfl_xor(p.y, m, 64);
        p.z += __shfl_xor(p.z, m, 64); p.w += __shfl_xor(p.w, m, 64);
      }
      float pv = (lane == 0) ? p.x : (lane == 1) ? p.y : (lane == 2) ? p.z : p.w;
      if (lane < 4) out[(size_t)lane*NENT + n] = pv + bc;
    } else {
      // fused next-layer entity matmul: y_next = xn @ We_next^T + be_next
      float4 yn = make_float4(bev, bev, bev, bev);
      if (SCHEME == 0) {
        *reinterpret_cast<float4*>(wsc + lane*4) = xn;
        #pragma unroll 8
        for (int k = 0; k < 64; ++k) {
          float4 u = *reinterpret_cast<const float4*>(wsc + k*4);  // uniform
          float  w = sWe[k*64 + lane];
          yn.x = fmaf(u.x, w, yn.x); yn.y = fmaf(u.y, w, yn.y);
          yn.z = fmaf(u.z, w, yn.z); yn.w = fmaf(u.w, w, yn.w);
        }
      } else {
        wsc[  0+lane] = xn.x; wsc[ 64+lane] = xn.y;
        wsc[128+lane] = xn.z; wsc[192+lane] = xn.w;
        #pragma unroll
        for (int k4 = 0; k4 < 16; ++k4) {
          float4 w4 = *reinterpret_cast<const float4*>(&sWe[lane*64 + ((k4 ^ (lane & 15)) * 4)]);
          float4 u0 = *reinterpret_cast<const float4*>(wsc +   0 + k4*4);
          float4 u1 = *reinterpret_cast<const float4*>(wsc +  64 + k4*4);
          float4 u2 = *reinterpret_cast<const float4*>(wsc + 128 + k4*4);
          float4 u3 = *reinterpret_cast<const float4*>(wsc + 192 + k4*4);
          yn.x = fmaf(u0.x, w4.x, yn.x); yn.x = fmaf(u0.y, w4.y, yn.x);
          yn.x = fmaf(u0.z, w4.z, yn.x); yn.x = fmaf(u0.w, w4.w, yn.x);
          yn.y = fmaf(u1.x, w4.x, yn.y); yn.y = fmaf(u1.y, w4.y, yn.y);
          yn.y = fmaf(u1.z, w4.z, yn.y); yn.y = fmaf(u1.w, w4.w, yn.y);
          yn.z = fmaf(u2.x, w4.x, yn.z); yn.z = fmaf(u2.y, w4.y, yn.z);
          yn.z = fmaf(u2.z, w4.z, yn.z); yn.z = fmaf(u2.w, w4.w, yn.z);
          yn.w = fmaf(u3.x, w4.x, yn.w); yn.w = fmaf(u3.y, w4.y, yn.w);
          yn.w = fmaf(u3.z, w4.z, yn.w); yn.w = fmaf(u3.w, w4.w, yn.w);
        }
      }
      *reinterpret_cast<float4*>(ynext + ((size_t)n*64 + lane)*4) = yn;
    }
  }
}

// ---------------- launch ----------------

extern "C" void kernel_launch(void* const* d_in, const int* in_sizes, int n_in,
                              void* d_out, int out_size, void* d_ws, size_t ws_size,
                              hipStream_t stream) {
  const int*   head = (const int*)  d_in[0];
  const int*   rel  = (const int*)  d_in[1];
  const int*   tri  = (const int*)  d_in[2];
  const float* ent  = (const float*)d_in[3];
  const float* qe   = (const float*)d_in[4];
  const float* rw   = (const float*)d_in[5];
  const float* We   = (const float*)d_in[6];
  const float* be   = (const float*)d_in[7];
  const float* Wl   = (const float*)d_in[8];
  const float* bl   = (const float*)d_in[9];
  const float* lg   = (const float*)d_in[10];
  const float* lb   = (const float*)d_in[11];
  const float* wc   = (const float*)d_in[12];
  const float* bc   = (const float*)d_in[13];

  char* ws = (char*)d_ws;
  size_t o = 0;
  auto alloc = [&](size_t bytes) { void* p = ws + o; o += (bytes + 255) & ~255ull; return p; };
  float*    ya   = (float*)   alloc((size_t)NENT*256*sizeof(float)); // 41 MB, [n][d][b]
  float*    yb   = (float*)   alloc((size_t)NENT*256*sizeof(float)); // 41 MB, [n][d][b]
  int*      cnt  = (int*)     alloc(NENT*sizeof(int));   // cnt, degm, cur contiguous
  int*      degm = (int*)     alloc(NENT*sizeof(int));   // (NENT*4 % 256 == 0)
  int*      cur  = (int*)     alloc(NENT*sizeof(int));
  int*      off  = (int*)     alloc((NENT+1)*sizeof(int));
  unsigned* ehr  = (unsigned*)alloc(NEDGE*sizeof(unsigned));
  (void)ws_size; (void)in_sizes; (void)n_in; (void)out_size;

  hipMemsetAsync(cnt, 0, (size_t)3*NENT*sizeof(int), stream);  // cnt, degm, cur

  k_count<<<(NEDGE+255)/256, 256, 0, stream>>>(tri, cnt, degm);
  k_scan <<<1, 1024, 0, stream>>>(cnt, off);
  k_fill <<<(NEDGE+255)/256, 256, 0, stream>>>(tri, off, cur, ehr);

  const int GRID = 1024;  // 4 blocks/CU x 8 waves = 32 waves/CU, grid-stride
  k_init<<<GRID, 512, 0, stream>>>(We, be, ya, ent, qe, head, rel, degm);

  for (int i = 0; i < NLAYER; ++i) {
    const float* src = (i % 2 == 0) ? ya : yb;
    float*       dst = (i % 2 == 0) ? yb : ya;
    const float* Wli = Wl + (size_t)i*4096;
    const float* bli = bl + (size_t)i*64;
    const float* rwi = rw + (size_t)i*401*64;
    const float* lgi = lg + (size_t)i*64;
    const float* lbi = lb + (size_t)i*64;
    const float* Wen = We + (size_t)(i+1)*4096;  // next layer's entity matmul
    const float* ben = be + (size_t)(i+1)*64;
    if (i == NLAYER-1)
      k_fused<0, true ><<<GRID, 512, 0, stream>>>(src, ehr, off, rwi, Wli, bli, lgi, lbi,
                                                  We, be, wc, bc, dst, (float*)d_out);
    else if (i % 2 == 0)   // layers 0,2,4 -> SCHEME 0 (A)
      k_fused<0, false><<<GRID, 512, 0, stream>>>(src, ehr, off, rwi, Wli, bli, lgi, lbi,
                                                  Wen, ben, wc, bc, dst, (float*)d_out);
    else                   // layers 1,3 -> SCHEME 1 (B)
      k_fused<1, false><<<GRID, 512, 0, stream>>>(src, ehr, off, rwi, Wli, bli, lgi, lbi,
                                                  Wen, ben, wc, bc, dst, (float*)d_out);
  }
}

// Round 10
// 753.110 us; speedup vs baseline: 1.8242x; 1.3454x over previous
//
#include <hip/hip_runtime.h>

#define NENT 40000
#define NRELH 200   /* (N_REL-1)/2 */
#define NLAYER 6
#define NEDGE 300000

// y layout: [node][d][b]  (idx = (n*64 + d)*4 + b): y[h][*][0..3] is a
// contiguous 1KB block one wave gathers with a single float4/lane instruction.

// ---------------- graph preprocessing (CSR build) ----------------

__global__ void k_count(const int* __restrict__ tri, int* __restrict__ cnt,
                        int* __restrict__ degm) {
  int e = blockIdx.x * blockDim.x + threadIdx.x;
  if (e >= NEDGE) return;
  int r = tri[3*e+1], t = tri[3*e+2];
  atomicAdd(&cnt[t], 1);
  if (r >= 1 && r < NRELH) atomicAdd(&degm[t], 1);
}

__global__ void k_scan(const int* __restrict__ cnt, int* __restrict__ off) {
  __shared__ int part[1024];
  int tid = threadIdx.x;
  int base = tid * 40;             // 1024*40 = 40960 >= NENT
  int s = 0;
  for (int i = 0; i < 40; ++i) { int idx = base + i; if (idx < NENT) s += cnt[idx]; }
  part[tid] = s;
  __syncthreads();
  for (int dd = 1; dd < 1024; dd <<= 1) {
    int v = (tid >= dd) ? part[tid - dd] : 0;
    __syncthreads();
    part[tid] += v;
    __syncthreads();
  }
  int run = part[tid] - s;
  for (int i = 0; i < 40; ++i) {
    int idx = base + i;
    if (idx < NENT) { off[idx] = run; run += cnt[idx]; }
  }
  if (tid == 1023) off[NENT] = part[1023];
}

__global__ void k_fill(const int* __restrict__ tri, const int* __restrict__ off,
                       int* __restrict__ cur, unsigned* __restrict__ ehr) {
  int e = blockIdx.x * blockDim.x + threadIdx.x;
  if (e >= NEDGE) return;
  int h = tri[3*e], r = tri[3*e+1], t = tri[3*e+2];
  int pos = off[t] + atomicAdd(&cur[t], 1);
  ehr[pos] = (unsigned)h | ((unsigned)r << 16);   // h < 65536, r < 512
}

// ---------------- layer 0 init: y0 = x0 @ We0^T + be0 ----------------
// 384-thread blocks (6 waves): 6 waves/EU quantum -> VGPR cap 85, no spill.

__global__ __launch_bounds__(384, 6)
void k_init(const float* __restrict__ We, const float* __restrict__ be,
            float* __restrict__ y, const float* __restrict__ ent,
            const float* __restrict__ qe, const int* __restrict__ head,
            const int* __restrict__ rel, const int* __restrict__ degm) {
  __shared__ float sWT[4096];   // WT[k][e] = We[e][k]  (16 KB)
  __shared__ float sc[1536];    // 6 waves x 256 floats scratch (6 KB)
  int tid = threadIdx.x, lane = tid & 63, wv = tid >> 6;
  for (int idx = tid; idx < 1024; idx += 384) {
    int e = idx >> 4, k4 = (idx & 15) * 4;
    float4 w = *reinterpret_cast<const float4*>(We + e*64 + k4);
    sWT[(k4+0)*64+e] = w.x; sWT[(k4+1)*64+e] = w.y;
    sWT[(k4+2)*64+e] = w.z; sWT[(k4+3)*64+e] = w.w;
  }
  __syncthreads();
  float bv = be[lane];
  int h0=head[0], h1=head[1], h2=head[2], h3=head[3];
  int r0=rel[0],  r1=rel[1],  r2=rel[2],  r3=rel[3];
  float* wsc = sc + wv*256;
  int stride = gridDim.x*6;
  for (int n = blockIdx.x*6 + wv; n < NENT; n += stride) {
    float basev = (degm[n] >= 3) ? ent[(size_t)n*64 + lane] : -0.375f; // 1/8-0.5
    float4 xv;
    xv.x = (h0==n) ? qe[r0*64+lane] : basev;
    xv.y = (h1==n) ? qe[r1*64+lane] : basev;
    xv.z = (h2==n) ? qe[r2*64+lane] : basev;
    xv.w = (h3==n) ? qe[r3*64+lane] : basev;
    *reinterpret_cast<float4*>(wsc + lane*4) = xv;      // lane holds x[d=lane][0..3]
    float4 acc = make_float4(bv, bv, bv, bv);
    #pragma unroll 8
    for (int k = 0; k < 64; ++k) {
      float4 u = *reinterpret_cast<const float4*>(wsc + k*4);  // uniform broadcast
      float  w = sWT[k*64 + lane];                             // lane = output e
      acc.x = fmaf(u.x, w, acc.x); acc.y = fmaf(u.y, w, acc.y);
      acc.z = fmaf(u.z, w, acc.z); acc.w = fmaf(u.w, w, acc.w);
    }
    *reinterpret_cast<float4*>(y + ((size_t)n*64 + lane)*4) = acc;
  }
}

// ---------------- fused layer kernel ----------------
// upd = segsum(relw[r] o y[h]);  z = upd @ Wl^T + bl + y[n];  xn = relu(LN(z));
// !LAST: y_next[n] = xn @ We_next^T + be_next      LAST: out[b][n] = xn . wcls + bc
// 384-thread blocks, LDS 38.9KB -> 4 blocks/CU = 24 waves/CU, VGPR cap 85 (no spill).

template<bool LAST>
__global__ __launch_bounds__(384, 6)
void k_fused(const float* __restrict__ y, const unsigned* __restrict__ ehr,
             const int* __restrict__ off, const float* __restrict__ relw,
             const float* __restrict__ Wl, const float* __restrict__ bl,
             const float* __restrict__ lng, const float* __restrict__ lnb,
             const float* __restrict__ Wen, const float* __restrict__ ben,
             const float* __restrict__ wcls, const float* __restrict__ bcls,
             float* __restrict__ ynext, float* __restrict__ out) {
  __shared__ float sWl[4096];   // Wl^T column-major (16 KB)
  __shared__ float sWe[4096];   // We_next^T (16 KB, unused when LAST)
  __shared__ float sc[1536];    // 6 waves x 256 floats scratch (6 KB)
  int tid = threadIdx.x, lane = tid & 63, wv = tid >> 6;
  for (int idx = tid; idx < 1024; idx += 384) {
    int e = idx >> 4, k4 = (idx & 15) * 4;
    float4 w = *reinterpret_cast<const float4*>(Wl + e*64 + k4);
    sWl[(k4+0)*64+e] = w.x; sWl[(k4+1)*64+e] = w.y;
    sWl[(k4+2)*64+e] = w.z; sWl[(k4+3)*64+e] = w.w;
    if (!LAST) {
      float4 v = *reinterpret_cast<const float4*>(Wen + e*64 + k4);
      sWe[(k4+0)*64+e] = v.x; sWe[(k4+1)*64+e] = v.y;
      sWe[(k4+2)*64+e] = v.z; sWe[(k4+3)*64+e] = v.w;
    }
  }
  __syncthreads();
  float blv = bl[lane], g = lng[lane], bb = lnb[lane];
  float bev = LAST ? 0.f : ben[lane];
  float wc  = LAST ? wcls[lane] : 0.f;
  float bc  = LAST ? bcls[0] : 0.f;
  float* wsc = sc + wv*256;
  int stride = gridDim.x*6;
  for (int n = blockIdx.x*6 + wv; n < NENT; n += stride) {
    int c0 = __builtin_amdgcn_readfirstlane(off[n]);
    int c1 = __builtin_amdgcn_readfirstlane(off[n+1]);
    // residual load issued early, overlaps the gather
    float4 res = *reinterpret_cast<const float4*>(y + ((size_t)n*64 + lane)*4);
    float4 a0 = make_float4(0,0,0,0), a1 = make_float4(0,0,0,0);
    for (int j = c0; j < c1; j += 4) {
      int j1 = (j+1 < c1) ? j+1 : j;
      int j2 = (j+2 < c1) ? j+2 : j;
      int j3 = (j+3 < c1) ? j+3 : j;
      unsigned e0 = ehr[j], e1 = ehr[j1], e2 = ehr[j2], e3 = ehr[j3];
      float m1 = (j+1 < c1) ? 1.f : 0.f;
      float m2 = (j+2 < c1) ? 1.f : 0.f;
      float m3 = (j+3 < c1) ? 1.f : 0.f;
      int ha = (int)(e0 & 0xffffu), ra = (int)(e0 >> 16);
      int hb = (int)(e1 & 0xffffu), rb = (int)(e1 >> 16);
      int hc = (int)(e2 & 0xffffu), rc = (int)(e2 >> 16);
      int hd = (int)(e3 & 0xffffu), rd = (int)(e3 >> 16);
      float w0 = relw[ra*64 + lane];
      float w1 = relw[rb*64 + lane] * m1;
      float w2 = relw[rc*64 + lane] * m2;
      float w3 = relw[rd*64 + lane] * m3;
      float4 v0 = *reinterpret_cast<const float4*>(y + ((size_t)ha*64 + lane)*4);
      float4 v1 = *reinterpret_cast<const float4*>(y + ((size_t)hb*64 + lane)*4);
      float4 v2 = *reinterpret_cast<const float4*>(y + ((size_t)hc*64 + lane)*4);
      float4 v3 = *reinterpret_cast<const float4*>(y + ((size_t)hd*64 + lane)*4);
      a0.x = fmaf(w0, v0.x, a0.x); a0.y = fmaf(w0, v0.y, a0.y);
      a0.z = fmaf(w0, v0.z, a0.z); a0.w = fmaf(w0, v0.w, a0.w);
      a1.x = fmaf(w1, v1.x, a1.x); a1.y = fmaf(w1, v1.y, a1.y);
      a1.z = fmaf(w1, v1.z, a1.z); a1.w = fmaf(w1, v1.w, a1.w);
      a0.x = fmaf(w2, v2.x, a0.x); a0.y = fmaf(w2, v2.y, a0.y);
      a0.z = fmaf(w2, v2.z, a0.z); a0.w = fmaf(w2, v2.w, a0.w);
      a1.x = fmaf(w3, v3.x, a1.x); a1.y = fmaf(w3, v3.y, a1.y);
      a1.z = fmaf(w3, v3.z, a1.z); a1.w = fmaf(w3, v3.w, a1.w);
    }
    float4 acc = make_float4(a0.x+a1.x, a0.y+a1.y, a0.z+a1.z, a0.w+a1.w);
    // z = upd @ Wl^T + bl + y[n]   (lane = output dim e)
    *reinterpret_cast<float4*>(wsc + lane*4) = acc;   // scratch [d][b]
    float4 z = make_float4(blv+res.x, blv+res.y, blv+res.z, blv+res.w);
    #pragma unroll 8
    for (int k = 0; k < 64; ++k) {
      float4 u = *reinterpret_cast<const float4*>(wsc + k*4);  // uniform
      float  w = sWl[k*64 + lane];                             // lane = e
      z.x = fmaf(u.x, w, z.x); z.y = fmaf(u.y, w, z.y);
      z.z = fmaf(u.z, w, z.z); z.w = fmaf(u.w, w, z.w);
    }
    // LayerNorm over the 64 lanes (feature dim), then ReLU
    float4 s = z;
    #pragma unroll
    for (int m = 32; m >= 1; m >>= 1) {
      s.x += __shfl_xor(s.x, m, 64); s.y += __shfl_xor(s.y, m, 64);
      s.z += __shfl_xor(s.z, m, 64); s.w += __shfl_xor(s.w, m, 64);
    }
    float4 dv = make_float4(z.x - s.x*0.015625f, z.y - s.y*0.015625f,
                            z.z - s.z*0.015625f, z.w - s.w*0.015625f);
    float4 q = make_float4(dv.x*dv.x, dv.y*dv.y, dv.z*dv.z, dv.w*dv.w);
    #pragma unroll
    for (int m = 32; m >= 1; m >>= 1) {
      q.x += __shfl_xor(q.x, m, 64); q.y += __shfl_xor(q.y, m, 64);
      q.z += __shfl_xor(q.z, m, 64); q.w += __shfl_xor(q.w, m, 64);
    }
    float4 xn;
    xn.x = fmaxf(dv.x * rsqrtf(q.x*0.015625f + 1e-5f) * g + bb, 0.f);
    xn.y = fmaxf(dv.y * rsqrtf(q.y*0.015625f + 1e-5f) * g + bb, 0.f);
    xn.z = fmaxf(dv.z * rsqrtf(q.z*0.015625f + 1e-5f) * g + bb, 0.f);
    xn.w = fmaxf(dv.w * rsqrtf(q.w*0.015625f + 1e-5f) * g + bb, 0.f);
    if (LAST) {
      float4 p = make_float4(xn.x*wc, xn.y*wc, xn.z*wc, xn.w*wc);
      #pragma unroll
      for (int m = 32; m >= 1; m >>= 1) {
        p.x += __shfl_xor(p.x, m, 64); p.y += __shfl_xor(p.y, m, 64);
        p.z += __shfl_xor(p.z, m, 64); p.w += __shfl_xor(p.w, m, 64);
      }
      float pv = (lane == 0) ? p.x : (lane == 1) ? p.y : (lane == 2) ? p.z : p.w;
      if (lane < 4) out[(size_t)lane*NENT + n] = pv + bc;
    } else {
      // fused next-layer entity matmul: y_next = xn @ We_next^T + be_next
      *reinterpret_cast<float4*>(wsc + lane*4) = xn;   // same wave, in-order
      float4 yn = make_float4(bev, bev, bev, bev);
      #pragma unroll 8
      for (int k = 0; k < 64; ++k) {
        float4 u = *reinterpret_cast<const float4*>(wsc + k*4);  // uniform
        float  w = sWe[k*64 + lane];
        yn.x = fmaf(u.x, w, yn.x); yn.y = fmaf(u.y, w, yn.y);
        yn.z = fmaf(u.z, w, yn.z); yn.w = fmaf(u.w, w, yn.w);
      }
      *reinterpret_cast<float4*>(ynext + ((size_t)n*64 + lane)*4) = yn;
    }
  }
}

// ---------------- launch ----------------

extern "C" void kernel_launch(void* const* d_in, const int* in_sizes, int n_in,
                              void* d_out, int out_size, void* d_ws, size_t ws_size,
                              hipStream_t stream) {
  const int*   head = (const int*)  d_in[0];
  const int*   rel  = (const int*)  d_in[1];
  const int*   tri  = (const int*)  d_in[2];
  const float* ent  = (const float*)d_in[3];
  const float* qe   = (const float*)d_in[4];
  const float* rw   = (const float*)d_in[5];
  const float* We   = (const float*)d_in[6];
  const float* be   = (const float*)d_in[7];
  const float* Wl   = (const float*)d_in[8];
  const float* bl   = (const float*)d_in[9];
  const float* lg   = (const float*)d_in[10];
  const float* lb   = (const float*)d_in[11];
  const float* wc   = (const float*)d_in[12];
  const float* bc   = (const float*)d_in[13];

  char* ws = (char*)d_ws;
  size_t o = 0;
  auto alloc = [&](size_t bytes) { void* p = ws + o; o += (bytes + 255) & ~255ull; return p; };
  float*    ya   = (float*)   alloc((size_t)NENT*256*sizeof(float)); // 41 MB, [n][d][b]
  float*    yb   = (float*)   alloc((size_t)NENT*256*sizeof(float)); // 41 MB, [n][d][b]
  int*      cnt  = (int*)     alloc(NENT*sizeof(int));   // cnt, degm, cur contiguous
  int*      degm = (int*)     alloc(NENT*sizeof(int));   // (NENT*4 % 256 == 0)
  int*      cur  = (int*)     alloc(NENT*sizeof(int));
  int*      off  = (int*)     alloc((NENT+1)*sizeof(int));
  unsigned* ehr  = (unsigned*)alloc(NEDGE*sizeof(unsigned));
  (void)ws_size; (void)in_sizes; (void)n_in; (void)out_size;

  hipMemsetAsync(cnt, 0, (size_t)3*NENT*sizeof(int), stream);  // cnt, degm, cur

  k_count<<<(NEDGE+255)/256, 256, 0, stream>>>(tri, cnt, degm);
  k_scan <<<1, 1024, 0, stream>>>(cnt, off);
  k_fill <<<(NEDGE+255)/256, 256, 0, stream>>>(tri, off, cur, ehr);

  const int GRID = 1024;  // 4 blocks/CU x 6 waves = 24 waves/CU, grid-stride
  k_init<<<GRID, 384, 0, stream>>>(We, be, ya, ent, qe, head, rel, degm);

  for (int i = 0; i < NLAYER; ++i) {
    const float* src = (i % 2 == 0) ? ya : yb;
    float*       dst = (i % 2 == 0) ? yb : ya;
    const float* Wli = Wl + (size_t)i*4096;
    const float* bli = bl + (size_t)i*64;
    const float* rwi = rw + (size_t)i*401*64;
    const float* lgi = lg + (size_t)i*64;
    const float* lbi = lb + (size_t)i*64;
    const float* Wen = We + (size_t)(i+1)*4096;  // next layer's entity matmul
    const float* ben = be + (size_t)(i+1)*64;
    if (i == NLAYER-1)
      k_fused<true ><<<GRID, 384, 0, stream>>>(src, ehr, off, rwi, Wli, bli, lgi, lbi,
                                               We, be, wc, bc, dst, (float*)d_out);
    else
      k_fused<false><<<GRID, 384, 0, stream>>>(src, ehr, off, rwi, Wli, bli, lgi, lbi,
                                               Wen, ben, wc, bc, dst, (float*)d_out);
  }
}